// Round 1
// baseline (224.512 us; speedup 1.0000x reference)
//
#include <hip/hip_runtime.h>
#include <stdint.h>

typedef int   i32x8 __attribute__((ext_vector_type(8)));
typedef float f32x4 __attribute__((ext_vector_type(4)));

#define B_ROWS 8192
#define D_DIM  512

// monotone float<->uint encoding: enc order == float order (so uint atomicMin
// == float min). f>=0: set sign bit; f<0: bitwise NOT.
__device__ __forceinline__ uint32_t enc_f32(float f) {
  uint32_t s = __float_as_uint(f);
  return (s & 0x80000000u) ? ~s : (s | 0x80000000u);
}
__device__ __forceinline__ float dec_f32(uint32_t e) {
  uint32_t s = (e & 0x80000000u) ? (e ^ 0x80000000u) : ~e;
  return __uint_as_float(s);
}

// ---------------------------------------------------------------------------
// Kernel 1: per-row normalize (fp32 -> fp8 e4m3) + cos(anchor, positive).
// Wave per row. Also inits minenc[r] = +inf encoding (replaces a memset node).
// ---------------------------------------------------------------------------
__global__ __launch_bounds__(256) void norm_kernel(
    const float* __restrict__ anchor, const float* __restrict__ positive,
    uint32_t* __restrict__ a8, uint32_t* __restrict__ p8,
    float* __restrict__ cos_ap, uint32_t* __restrict__ minenc)
{
  const int wave = threadIdx.x >> 6, lane = threadIdx.x & 63;
  const int r = blockIdx.x * 4 + wave;

  const float4* av = (const float4*)(anchor   + (size_t)r * D_DIM) + lane * 2;
  const float4* pv = (const float4*)(positive + (size_t)r * D_DIM) + lane * 2;
  float4 a0 = av[0], a1 = av[1];
  float4 p0 = pv[0], p1 = pv[1];

  float sa = a0.x*a0.x + a0.y*a0.y + a0.z*a0.z + a0.w*a0.w
           + a1.x*a1.x + a1.y*a1.y + a1.z*a1.z + a1.w*a1.w;
  float sp = p0.x*p0.x + p0.y*p0.y + p0.z*p0.z + p0.w*p0.w
           + p1.x*p1.x + p1.y*p1.y + p1.z*p1.z + p1.w*p1.w;
  float dp = a0.x*p0.x + a0.y*p0.y + a0.z*p0.z + a0.w*p0.w
           + a1.x*p1.x + a1.y*p1.y + a1.z*p1.z + a1.w*p1.w;

#pragma unroll
  for (int d = 1; d < 64; d <<= 1) {
    sa += __shfl_xor(sa, d);
    sp += __shfl_xor(sp, d);
    dp += __shfl_xor(dp, d);
  }

  const float na = sqrtf(sa), np = sqrtf(sp);
  const float ia = 1.0f / na, ip = 1.0f / np;

  float na0 = a0.x*ia, na1 = a0.y*ia, na2 = a0.z*ia, na3 = a0.w*ia;
  float na4 = a1.x*ia, na5 = a1.y*ia, na6 = a1.z*ia, na7 = a1.w*ia;
  float np0 = p0.x*ip, np1 = p0.y*ip, np2 = p0.z*ip, np3 = p0.w*ip;
  float np4 = p1.x*ip, np5 = p1.y*ip, np6 = p1.z*ip, np7 = p1.w*ip;

  uint32_t aw0 = __builtin_amdgcn_cvt_pk_fp8_f32(na0, na1, 0,  false);
  aw0          = __builtin_amdgcn_cvt_pk_fp8_f32(na2, na3, aw0, true);
  uint32_t aw1 = __builtin_amdgcn_cvt_pk_fp8_f32(na4, na5, 0,  false);
  aw1          = __builtin_amdgcn_cvt_pk_fp8_f32(na6, na7, aw1, true);
  uint32_t pw0 = __builtin_amdgcn_cvt_pk_fp8_f32(np0, np1, 0,  false);
  pw0          = __builtin_amdgcn_cvt_pk_fp8_f32(np2, np3, pw0, true);
  uint32_t pw1 = __builtin_amdgcn_cvt_pk_fp8_f32(np4, np5, 0,  false);
  pw1          = __builtin_amdgcn_cvt_pk_fp8_f32(np6, np7, pw1, true);

  ((uint2*)a8)[(size_t)r * 64 + lane] = make_uint2(aw0, aw1);
  ((uint2*)p8)[(size_t)r * 64 + lane] = make_uint2(pw0, pw1);

  if (lane == 0) {
    cos_ap[r] = dp / fmaxf(na * np, 1e-8f);
    minenc[r] = 0xFFFFFFFFu;   // +inf in monotone encoding
  }
}

// ---------------------------------------------------------------------------
// global -> LDS direct load, 16B per lane (dest = wave-uniform base + lane*16).
// ---------------------------------------------------------------------------
__device__ __forceinline__ void load16_to_lds(const void* g, void* l) {
  __builtin_amdgcn_global_load_lds(
      (__attribute__((address_space(1))) uint32_t*)(uintptr_t)(g),
      (__attribute__((address_space(3))) uint32_t*)(uintptr_t)(l),
      16, 0, 0);
}

// ---------------------------------------------------------------------------
// Kernel 2: 128x128 fp8 MX-MFMA tile of sim = A_n * P_n^T (scale=1.0), fused
// diagonal-masked row-min -> device atomicMin on encoded floats.
//
// R4 change: A fragments are loaded DIRECTLY from global (per-XCD L2-resident
// thanks to the block swizzle: 512 KB A-slice per XCD). Only P is staged in
// LDS (double-buffered, XOR-swizzled). LDS: 65 KB -> 33 KB, so occupancy
// doubles to 4 blocks/CU (16 waves). R3 counters said latency-bound
// (MfmaUtil==VALUBusy==22%, Occ 19% at 2 blocks/CU); this trades cheap L2 BW
// (~23 TB/s demand vs 34.5 ceiling) for 2x the wave-level latency hiding, and
// halves LDS read traffic + bank conflicts.
//
// Block swizzle: xcd = bid&7 owns A-rowTiles [xcd*8, xcd*8+8) for ALL 64
// colTiles (A stays L2-resident: 512 KB/XCD; P streams once: 4 MB/XCD).
// ---------------------------------------------------------------------------
__global__ __launch_bounds__(256, 4) void simmin_kernel(
    const uint8_t* __restrict__ a8, const uint8_t* __restrict__ p8,
    uint32_t* __restrict__ minenc)
{
  __shared__ __attribute__((aligned(16))) uint8_t Plds[2][128 * 128];
  __shared__ float redmin[256];

  const int tid  = threadIdx.x;
  const int lane = tid & 63;
  const int wave = tid >> 6;
  const int waveM = wave >> 1, waveN = wave & 1;
  const int quad = lane >> 4;
  const int l15  = lane & 15;

  // super-tile swizzle (see header comment)
  const int bid = blockIdx.x;
  const int blockRow = (bid & 7) * 8 + ((bid >> 3) & 7);
  const int blockCol = bid >> 6;

  f32x4 acc[4][4];
  const f32x4 zero = {0.f, 0.f, 0.f, 0.f};
#pragma unroll
  for (int i = 0; i < 4; i++)
#pragma unroll
    for (int j = 0; j < 4; j++) acc[i][j] = zero;

  // P staging: chunk = 8 rows x 128B; lane i: row = i/8, XOR-swizzled k-slot
  // fetched pre-swizzled on the global side (LDS side must stay contiguous).
  const int srow = lane >> 3;
  const int sk   = (lane & 7) ^ srow;
  const uint8_t* pBase = p8 + (size_t)(blockCol * 128) * D_DIM;

  auto stage = [&](int k0, int buf) {
#pragma unroll
    for (int c = 0; c < 4; c++) {
      const int chunk = wave * 4 + c;       // 0..15
      const size_t goff = (size_t)(chunk * 8 + srow) * D_DIM + k0 + sk * 16;
      load16_to_lds(pBase + goff, &Plds[buf][chunk * 1024]);
    }
  };

  // A fragment base: lane reads row (blockRow*128 + waveM*64 + mf*16 + l15),
  // bytes [k0 + quad*32, k0 + quad*32 + 32). Identical data to the old
  // LDS-staged path (stage-XOR and read-XOR cancelled), now served by L2.
  const uint8_t* aFragBase =
      a8 + (size_t)(blockRow * 128 + waveM * 64 + l15) * D_DIM + quad * 32;

  stage(0, 0);

#pragma unroll
  for (int k = 0; k < 4; k++) {
    const int buf = k & 1;
    const int k0  = k * 128;

    // A fragments from global: issue BEFORE the barrier so their L2 latency
    // hides under the barrier's vmcnt(0) drain of the P staging loads.
    i32x8 af[4];
#pragma unroll
    for (int mf = 0; mf < 4; mf++) {
      const uint8_t* ap = aFragBase + (size_t)(mf * 16) * D_DIM + k0;
      const int4 lo = *(const int4*)(ap);
      const int4 hi = *(const int4*)(ap + 16);
      af[mf] = (i32x8){lo.x, lo.y, lo.z, lo.w, hi.x, hi.y, hi.z, hi.w};
    }

    __syncthreads();  // P tile k staged; also fences reads of buf from k-2

    i32x8 bfr[4];
#pragma unroll
    for (int nf = 0; nf < 4; nf++) {
      const int r = waveN * 64 + nf * 16 + l15;
      const int rx = r & 7;
      const int4 lo = *(const int4*)&Plds[buf][r * 128 + (((quad * 2 + 0) ^ rx) * 16)];
      const int4 hi = *(const int4*)&Plds[buf][r * 128 + (((quad * 2 + 1) ^ rx) * 16)];
      bfr[nf] = (i32x8){lo.x, lo.y, lo.z, lo.w, hi.x, hi.y, hi.z, hi.w};
    }

    if (k < 3) stage(k0 + 128, buf ^ 1);  // prefetch next P tile

#pragma unroll
    for (int mf = 0; mf < 4; mf++)
#pragma unroll
      for (int nf = 0; nf < 4; nf++)
        acc[mf][nf] = __builtin_amdgcn_mfma_scale_f32_16x16x128_f8f6f4(
            af[mf], bfr[nf], acc[mf][nf],
            0, 0,                 // cbsz=fp8(e4m3) A, blgp=fp8(e4m3) B
            0, 0x7F7F7F7F,        // scale A (2^0)
            0, 0x7F7F7F7F);       // scale B (2^0)
  }

  // ---- fused epilogue: per-row min over this block's 128 cols, diag masked
  const int rowTileBase = blockRow * 128 + waveM * 64;
  const int colTileBase = blockCol * 128 + waveN * 64;

  float rm[4][4];
#pragma unroll
  for (int mf = 0; mf < 4; mf++)
#pragma unroll
    for (int r = 0; r < 4; r++) rm[mf][r] = 3.0e38f;

#pragma unroll
  for (int mf = 0; mf < 4; mf++) {
#pragma unroll
    for (int nf = 0; nf < 4; nf++) {
      const int col = colTileBase + nf * 16 + l15;
#pragma unroll
      for (int r = 0; r < 4; r++) {
        const int row = rowTileBase + mf * 16 + quad * 4 + r;
        const float v = acc[mf][nf][r];
        rm[mf][r] = (row == col) ? rm[mf][r] : fminf(rm[mf][r], v);
      }
    }
  }
#pragma unroll
  for (int d = 1; d < 16; d <<= 1)
#pragma unroll
    for (int mf = 0; mf < 4; mf++)
#pragma unroll
      for (int r = 0; r < 4; r++)
        rm[mf][r] = fminf(rm[mf][r], __shfl_xor(rm[mf][r], d));

  if (l15 == 0) {
#pragma unroll
    for (int mf = 0; mf < 4; mf++)
#pragma unroll
      for (int r = 0; r < 4; r++)
        redmin[waveN * 128 + waveM * 64 + mf * 16 + quad * 4 + r] = rm[mf][r];
  }
  __syncthreads();

  if (tid < 128) {
    const float m = fminf(redmin[tid], redmin[128 + tid]);
    atomicMin(&minenc[blockRow * 128 + tid], enc_f32(m));  // device-scope
  }
}

// ---------------------------------------------------------------------------
// Kernel 3: single block (1024 thr) — decode row-mins, loss, mean, store.
// ---------------------------------------------------------------------------
__global__ __launch_bounds__(1024) void finalize_kernel(
    const uint32_t* __restrict__ minenc, const float* __restrict__ cos_ap,
    float* __restrict__ out)
{
  float sum = 0.0f;
#pragma unroll
  for (int r = threadIdx.x; r < B_ROWS; r += 1024)
    sum += fmaxf(0.0f, 1.0f + cos_ap[r] - dec_f32(minenc[r]));

#pragma unroll
  for (int d = 1; d < 64; d <<= 1) sum += __shfl_xor(sum, d);
  __shared__ float s[16];
  if ((threadIdx.x & 63) == 0) s[threadIdx.x >> 6] = sum;
  __syncthreads();
  if (threadIdx.x < 64) {
    float t = (threadIdx.x < 16) ? s[threadIdx.x] : 0.0f;
#pragma unroll
    for (int d = 1; d < 16; d <<= 1) t += __shfl_xor(t, d);
    if (threadIdx.x == 0) out[0] = t * (1.0f / (float)B_ROWS);
  }
}

// ---------------------------------------------------------------------------
extern "C" void kernel_launch(void* const* d_in, const int* in_sizes, int n_in,
                              void* d_out, int out_size, void* d_ws, size_t ws_size,
                              hipStream_t stream) {
  const float* anchor   = (const float*)d_in[0];
  const float* positive = (const float*)d_in[1];

  char* ws = (char*)d_ws;
  uint32_t* a8     = (uint32_t*)(ws);                                // 4 MB
  uint32_t* p8     = (uint32_t*)(ws + (4ull << 20));                 // 4 MB
  float*    cos_ap = (float*)(ws + (8ull << 20));                    // 32 KB
  uint32_t* minenc = (uint32_t*)(ws + (8ull << 20) + (32ull << 10)); // 32 KB
  float*    out = (float*)d_out;

  norm_kernel<<<B_ROWS / 4, 256, 0, stream>>>(anchor, positive, a8, p8,
                                              cos_ap, minenc);
  simmin_kernel<<<4096, 256, 0, stream>>>((const uint8_t*)a8,
                                          (const uint8_t*)p8, minenc);
  finalize_kernel<<<1, 1024, 0, stream>>>(minenc, cos_ap, out);
}

// Round 2
// 152.169 us; speedup vs baseline: 1.4754x; 1.4754x over previous
//
#include <hip/hip_runtime.h>
#include <stdint.h>

typedef int   i32x8 __attribute__((ext_vector_type(8)));
typedef float f32x4 __attribute__((ext_vector_type(4)));

#define B_ROWS 8192
#define D_DIM  512

// monotone float<->uint encoding: enc order == float order (so uint atomicMin
// == float min). f>=0: set sign bit; f<0: bitwise NOT.
__device__ __forceinline__ uint32_t enc_f32(float f) {
  uint32_t s = __float_as_uint(f);
  return (s & 0x80000000u) ? ~s : (s | 0x80000000u);
}
__device__ __forceinline__ float dec_f32(uint32_t e) {
  uint32_t s = (e & 0x80000000u) ? (e ^ 0x80000000u) : ~e;
  return __uint_as_float(s);
}

// ---------------------------------------------------------------------------
// Kernel 1: per-row normalize (fp32 -> fp8 e4m3) + cos(anchor, positive).
// Wave per row. Also inits minenc[r] = +inf encoding (replaces a memset node).
// ---------------------------------------------------------------------------
__global__ __launch_bounds__(256) void norm_kernel(
    const float* __restrict__ anchor, const float* __restrict__ positive,
    uint32_t* __restrict__ a8, uint32_t* __restrict__ p8,
    float* __restrict__ cos_ap, uint32_t* __restrict__ minenc)
{
  const int wave = threadIdx.x >> 6, lane = threadIdx.x & 63;
  const int r = blockIdx.x * 4 + wave;

  const float4* av = (const float4*)(anchor   + (size_t)r * D_DIM) + lane * 2;
  const float4* pv = (const float4*)(positive + (size_t)r * D_DIM) + lane * 2;
  float4 a0 = av[0], a1 = av[1];
  float4 p0 = pv[0], p1 = pv[1];

  float sa = a0.x*a0.x + a0.y*a0.y + a0.z*a0.z + a0.w*a0.w
           + a1.x*a1.x + a1.y*a1.y + a1.z*a1.z + a1.w*a1.w;
  float sp = p0.x*p0.x + p0.y*p0.y + p0.z*p0.z + p0.w*p0.w
           + p1.x*p1.x + p1.y*p1.y + p1.z*p1.z + p1.w*p1.w;
  float dp = a0.x*p0.x + a0.y*p0.y + a0.z*p0.z + a0.w*p0.w
           + a1.x*p1.x + a1.y*p1.y + a1.z*p1.z + a1.w*p1.w;

#pragma unroll
  for (int d = 1; d < 64; d <<= 1) {
    sa += __shfl_xor(sa, d);
    sp += __shfl_xor(sp, d);
    dp += __shfl_xor(dp, d);
  }

  const float na = sqrtf(sa), np = sqrtf(sp);
  const float ia = 1.0f / na, ip = 1.0f / np;

  float na0 = a0.x*ia, na1 = a0.y*ia, na2 = a0.z*ia, na3 = a0.w*ia;
  float na4 = a1.x*ia, na5 = a1.y*ia, na6 = a1.z*ia, na7 = a1.w*ia;
  float np0 = p0.x*ip, np1 = p0.y*ip, np2 = p0.z*ip, np3 = p0.w*ip;
  float np4 = p1.x*ip, np5 = p1.y*ip, np6 = p1.z*ip, np7 = p1.w*ip;

  uint32_t aw0 = __builtin_amdgcn_cvt_pk_fp8_f32(na0, na1, 0,  false);
  aw0          = __builtin_amdgcn_cvt_pk_fp8_f32(na2, na3, aw0, true);
  uint32_t aw1 = __builtin_amdgcn_cvt_pk_fp8_f32(na4, na5, 0,  false);
  aw1          = __builtin_amdgcn_cvt_pk_fp8_f32(na6, na7, aw1, true);
  uint32_t pw0 = __builtin_amdgcn_cvt_pk_fp8_f32(np0, np1, 0,  false);
  pw0          = __builtin_amdgcn_cvt_pk_fp8_f32(np2, np3, pw0, true);
  uint32_t pw1 = __builtin_amdgcn_cvt_pk_fp8_f32(np4, np5, 0,  false);
  pw1          = __builtin_amdgcn_cvt_pk_fp8_f32(np6, np7, pw1, true);

  ((uint2*)a8)[(size_t)r * 64 + lane] = make_uint2(aw0, aw1);
  ((uint2*)p8)[(size_t)r * 64 + lane] = make_uint2(pw0, pw1);

  if (lane == 0) {
    cos_ap[r] = dp / fmaxf(na * np, 1e-8f);
    minenc[r] = 0xFFFFFFFFu;   // +inf in monotone encoding
  }
}

// ---------------------------------------------------------------------------
// global -> LDS direct load, 16B per lane (dest = wave-uniform base + lane*16).
// ---------------------------------------------------------------------------
__device__ __forceinline__ void load16_to_lds(const void* g, void* l) {
  __builtin_amdgcn_global_load_lds(
      (__attribute__((address_space(1))) uint32_t*)(uintptr_t)(g),
      (__attribute__((address_space(3))) uint32_t*)(uintptr_t)(l),
      16, 0, 0);
}

// ---------------------------------------------------------------------------
// Kernel 2: 128x128 fp8 MX-MFMA tile of sim = A_n * P_n^T (scale=1.0), fused
// diagonal-masked row-min -> device atomicMin on encoded floats.
//
// Structure (R1, verified correct): A fragments load DIRECTLY from global
// (per-XCD L2-resident via block swizzle: 512 KB A-slice/XCD). Only P staged
// in LDS (double-buffered, XOR-swizzled) -> 34 KB LDS.
//
// R2 fix: __launch_bounds__(256, 3) not (256, 4). R1's (256,4) capped the
// unified VGPR budget at 128 < ~152 working set (64 acc + 32 af + 32 bfr +
// addressing) -> massive scratch spill (WRITE_SIZE 2 MB -> 411 MB, FETCH
// 216 MB, hbm 51% peak, MfmaUtil 8.5%). Cap 512/3 = 170 fits the working
// set with headroom; 3 blocks/CU (1.5x R0) with zero spill.
//
// Block swizzle: xcd = bid&7 owns A-rowTiles [xcd*8, xcd*8+8) for ALL 64
// colTiles (A stays L2-resident: 512 KB/XCD; P streams once: 4 MB/XCD).
// ---------------------------------------------------------------------------
__global__ __launch_bounds__(256, 3) void simmin_kernel(
    const uint8_t* __restrict__ a8, const uint8_t* __restrict__ p8,
    uint32_t* __restrict__ minenc)
{
  __shared__ __attribute__((aligned(16))) uint8_t Plds[2][128 * 128];
  __shared__ float redmin[256];

  const int tid  = threadIdx.x;
  const int lane = tid & 63;
  const int wave = tid >> 6;
  const int waveM = wave >> 1, waveN = wave & 1;
  const int quad = lane >> 4;
  const int l15  = lane & 15;

  // super-tile swizzle (see header comment)
  const int bid = blockIdx.x;
  const int blockRow = (bid & 7) * 8 + ((bid >> 3) & 7);
  const int blockCol = bid >> 6;

  f32x4 acc[4][4];
  const f32x4 zero = {0.f, 0.f, 0.f, 0.f};
#pragma unroll
  for (int i = 0; i < 4; i++)
#pragma unroll
    for (int j = 0; j < 4; j++) acc[i][j] = zero;

  // P staging: chunk = 8 rows x 128B; lane i: row = i/8, XOR-swizzled k-slot
  // fetched pre-swizzled on the global side (LDS side must stay contiguous).
  const int srow = lane >> 3;
  const int sk   = (lane & 7) ^ srow;
  const uint8_t* pBase = p8 + (size_t)(blockCol * 128) * D_DIM;

  auto stage = [&](int k0, int buf) {
#pragma unroll
    for (int c = 0; c < 4; c++) {
      const int chunk = wave * 4 + c;       // 0..15
      const size_t goff = (size_t)(chunk * 8 + srow) * D_DIM + k0 + sk * 16;
      load16_to_lds(pBase + goff, &Plds[buf][chunk * 1024]);
    }
  };

  // A fragment base: lane reads row (blockRow*128 + waveM*64 + mf*16 + l15),
  // bytes [k0 + quad*32, k0 + quad*32 + 32). Identical data to the old
  // LDS-staged path (stage-XOR and read-XOR cancelled), served by L2.
  const uint8_t* aFragBase =
      a8 + (size_t)(blockRow * 128 + waveM * 64 + l15) * D_DIM + quad * 32;

  stage(0, 0);

#pragma unroll
  for (int k = 0; k < 4; k++) {
    const int buf = k & 1;
    const int k0  = k * 128;

    // A fragments from global: issue BEFORE the barrier so their L2 latency
    // hides under the barrier's vmcnt(0) drain of the P staging loads.
    i32x8 af[4];
#pragma unroll
    for (int mf = 0; mf < 4; mf++) {
      const uint8_t* ap = aFragBase + (size_t)(mf * 16) * D_DIM + k0;
      const int4 lo = *(const int4*)(ap);
      const int4 hi = *(const int4*)(ap + 16);
      af[mf] = (i32x8){lo.x, lo.y, lo.z, lo.w, hi.x, hi.y, hi.z, hi.w};
    }

    __syncthreads();  // P tile k staged; also fences reads of buf from k-2

    i32x8 bfr[4];
#pragma unroll
    for (int nf = 0; nf < 4; nf++) {
      const int r = waveN * 64 + nf * 16 + l15;
      const int rx = r & 7;
      const int4 lo = *(const int4*)&Plds[buf][r * 128 + (((quad * 2 + 0) ^ rx) * 16)];
      const int4 hi = *(const int4*)&Plds[buf][r * 128 + (((quad * 2 + 1) ^ rx) * 16)];
      bfr[nf] = (i32x8){lo.x, lo.y, lo.z, lo.w, hi.x, hi.y, hi.z, hi.w};
    }

    if (k < 3) stage(k0 + 128, buf ^ 1);  // prefetch next P tile

#pragma unroll
    for (int mf = 0; mf < 4; mf++)
#pragma unroll
      for (int nf = 0; nf < 4; nf++)
        acc[mf][nf] = __builtin_amdgcn_mfma_scale_f32_16x16x128_f8f6f4(
            af[mf], bfr[nf], acc[mf][nf],
            0, 0,                 // cbsz=fp8(e4m3) A, blgp=fp8(e4m3) B
            0, 0x7F7F7F7F,        // scale A (2^0)
            0, 0x7F7F7F7F);       // scale B (2^0)
  }

  // ---- fused epilogue: per-row min over this block's 128 cols, diag masked
  const int rowTileBase = blockRow * 128 + waveM * 64;
  const int colTileBase = blockCol * 128 + waveN * 64;

  float rm[4][4];
#pragma unroll
  for (int mf = 0; mf < 4; mf++)
#pragma unroll
    for (int r = 0; r < 4; r++) rm[mf][r] = 3.0e38f;

#pragma unroll
  for (int mf = 0; mf < 4; mf++) {
#pragma unroll
    for (int nf = 0; nf < 4; nf++) {
      const int col = colTileBase + nf * 16 + l15;
#pragma unroll
      for (int r = 0; r < 4; r++) {
        const int row = rowTileBase + mf * 16 + quad * 4 + r;
        const float v = acc[mf][nf][r];
        rm[mf][r] = (row == col) ? rm[mf][r] : fminf(rm[mf][r], v);
      }
    }
  }
#pragma unroll
  for (int d = 1; d < 16; d <<= 1)
#pragma unroll
    for (int mf = 0; mf < 4; mf++)
#pragma unroll
      for (int r = 0; r < 4; r++)
        rm[mf][r] = fminf(rm[mf][r], __shfl_xor(rm[mf][r], d));

  if (l15 == 0) {
#pragma unroll
    for (int mf = 0; mf < 4; mf++)
#pragma unroll
      for (int r = 0; r < 4; r++)
        redmin[waveN * 128 + waveM * 64 + mf * 16 + quad * 4 + r] = rm[mf][r];
  }
  __syncthreads();

  if (tid < 128) {
    const float m = fminf(redmin[tid], redmin[128 + tid]);
    atomicMin(&minenc[blockRow * 128 + tid], enc_f32(m));  // device-scope
  }
}

// ---------------------------------------------------------------------------
// Kernel 3: single block (1024 thr) — decode row-mins, loss, mean, store.
// ---------------------------------------------------------------------------
__global__ __launch_bounds__(1024) void finalize_kernel(
    const uint32_t* __restrict__ minenc, const float* __restrict__ cos_ap,
    float* __restrict__ out)
{
  float sum = 0.0f;
#pragma unroll
  for (int r = threadIdx.x; r < B_ROWS; r += 1024)
    sum += fmaxf(0.0f, 1.0f + cos_ap[r] - dec_f32(minenc[r]));

#pragma unroll
  for (int d = 1; d < 64; d <<= 1) sum += __shfl_xor(sum, d);
  __shared__ float s[16];
  if ((threadIdx.x & 63) == 0) s[threadIdx.x >> 6] = sum;
  __syncthreads();
  if (threadIdx.x < 64) {
    float t = (threadIdx.x < 16) ? s[threadIdx.x] : 0.0f;
#pragma unroll
    for (int d = 1; d < 16; d <<= 1) t += __shfl_xor(t, d);
    if (threadIdx.x == 0) out[0] = t * (1.0f / (float)B_ROWS);
  }
}

// ---------------------------------------------------------------------------
extern "C" void kernel_launch(void* const* d_in, const int* in_sizes, int n_in,
                              void* d_out, int out_size, void* d_ws, size_t ws_size,
                              hipStream_t stream) {
  const float* anchor   = (const float*)d_in[0];
  const float* positive = (const float*)d_in[1];

  char* ws = (char*)d_ws;
  uint32_t* a8     = (uint32_t*)(ws);                                // 4 MB
  uint32_t* p8     = (uint32_t*)(ws + (4ull << 20));                 // 4 MB
  float*    cos_ap = (float*)(ws + (8ull << 20));                    // 32 KB
  uint32_t* minenc = (uint32_t*)(ws + (8ull << 20) + (32ull << 10)); // 32 KB
  float*    out = (float*)d_out;

  norm_kernel<<<B_ROWS / 4, 256, 0, stream>>>(anchor, positive, a8, p8,
                                              cos_ap, minenc);
  simmin_kernel<<<4096, 256, 0, stream>>>((const uint8_t*)a8,
                                          (const uint8_t*)p8, minenc);
  finalize_kernel<<<1, 1024, 0, stream>>>(minenc, cos_ap, out);
}